// Round 1
// baseline (822.801 us; speedup 1.0000x reference)
//
#include <hip/hip_runtime.h>
#include <stdint.h>

#define DEVI __device__ __forceinline__

typedef __attribute__((ext_vector_type(4))) float f32x4;
typedef __attribute__((ext_vector_type(8))) short bf16x8;
typedef __attribute__((ext_vector_type(4))) unsigned short u16x4;

DEVI unsigned short f2bf(float x) {
  union { float f; uint32_t u; } v; v.f = x;
  uint32_t r = v.u + 0x7FFFu + ((v.u >> 16) & 1u);  // RNE
  return (unsigned short)(r >> 16);
}
DEVI float bf2f(unsigned short h) {
  union { uint32_t u; float f; } v; v.u = ((uint32_t)h) << 16;
  return v.f;
}

DEVI void async16(const void* g, void* l) {
  __builtin_amdgcn_global_load_lds((__attribute__((address_space(1))) void*)g,
                                   (__attribute__((address_space(3))) void*)l,
                                   16, 0, 0);
}

// ---------------- P0: fp32 -> bf16 hi/lo split ----------------
__global__ void k_split(const float* __restrict__ x, unsigned short* __restrict__ hi,
                        unsigned short* __restrict__ lo, const long n4) {
  const long i = (long)blockIdx.x * 256 + threadIdx.x;
  if (i >= n4) return;
  const f32x4 v = ((const f32x4*)x)[i];
  u16x4 H, L;
#pragma unroll
  for (int j = 0; j < 4; ++j) {
    H[j] = f2bf(v[j]);
    L[j] = f2bf(v[j] - bf2f(H[j]));
  }
  ((u16x4*)hi)[i] = H;
  ((u16x4*)lo)[i] = L;
}

// ---------------- GEMM: C = A * B^T  (A: [M][Kd], B: [Nn][Kd], C: [M][Nn]) ----
// 128x128 tile, BK=32, 4 waves (2x2), 4x4 MFMA 16x16x32 tiles per wave.
// LDS layout per buffer: chunk (kg,row) at ushort index (kg*128+row)*8,
// holding X[row][kg*8 .. kg*8+8) -> conflict-free ds_read_b128 frags and
// compatible with global_load_lds wave-uniform-base + lane*16.
template<bool SPLIT, bool OUTSPLIT>
__global__ __launch_bounds__(256, 2)
void k_gemm_bt(const unsigned short* __restrict__ Ah, const unsigned short* __restrict__ Al,
               const unsigned short* __restrict__ Bh, const unsigned short* __restrict__ Bl,
               const float* __restrict__ bias,
               float* __restrict__ Cf, unsigned short* __restrict__ Ch,
               unsigned short* __restrict__ Cl,
               const int Kd, const int Nn,
               const long sA, const long sB, const long sC) {
  __shared__ __align__(16) unsigned short smem[SPLIT ? 16384 : 8192];
  const int tid  = threadIdx.x;
  const int lane = tid & 63;
  const int wave = tid >> 6;
  const int wm = wave >> 1, wn = wave & 1;
  const int m16 = lane & 15, quad = lane >> 4;

  const long aTile = (long)blockIdx.z * sA + (long)blockIdx.x * 128 * Kd;
  const long bTile = (long)blockIdx.z * sB + (long)blockIdx.y * 128 * Kd;

  // staging chunks: t in {0,1}: c = t*256 + tid ; r = c&127 ; kg = c>>7
  const int rs  = tid & 127;
  const int kg0 = tid >> 7;
  const int kg1 = 2 + (tid >> 7);
  const long aoff0 = (long)rs * Kd + kg0 * 8;
  const long aoff1 = (long)rs * Kd + kg1 * 8;

  const unsigned short* gAh0 = Ah + aTile + aoff0;
  const unsigned short* gAh1 = Ah + aTile + aoff1;
  const unsigned short* gBh0 = Bh + bTile + aoff0;
  const unsigned short* gBh1 = Bh + bTile + aoff1;
  const unsigned short* gAl0 = SPLIT ? (Al + aTile + aoff0) : (const unsigned short*)0;
  const unsigned short* gAl1 = SPLIT ? (Al + aTile + aoff1) : (const unsigned short*)0;
  const unsigned short* gBl0 = SPLIT ? (Bl + bTile + aoff0) : (const unsigned short*)0;
  const unsigned short* gBl1 = SPLIT ? (Bl + bTile + aoff1) : (const unsigned short*)0;

  unsigned short* sAh = smem;
  unsigned short* sBh = smem + 4096;
  unsigned short* sAl = smem + (SPLIT ? 8192 : 0);
  unsigned short* sBl = smem + (SPLIT ? 12288 : 0);
  const int lw0 = (wave * 64) * 8;         // ushort offset, t=0
  const int lw1 = (256 + wave * 64) * 8;   // t=1

  f32x4 acc[4][4];
#pragma unroll
  for (int i = 0; i < 4; ++i)
#pragma unroll
    for (int j = 0; j < 4; ++j) acc[i][j] = (f32x4){0.0f, 0.0f, 0.0f, 0.0f};

  const int arow = wm * 64 + m16;
  const int brow = wn * 64 + m16;
  const bf16x8* fAh = (const bf16x8*)sAh;
  const bf16x8* fBh = (const bf16x8*)sBh;
  const bf16x8* fAl = (const bf16x8*)sAl;
  const bf16x8* fBl = (const bf16x8*)sBl;

  for (int kt = 0; kt < Kd; kt += 32) {
    __syncthreads();
    async16(gAh0 + kt, sAh + lw0);
    async16(gAh1 + kt, sAh + lw1);
    async16(gBh0 + kt, sBh + lw0);
    async16(gBh1 + kt, sBh + lw1);
    if (SPLIT) {
      async16(gAl0 + kt, sAl + lw0);
      async16(gAl1 + kt, sAl + lw1);
      async16(gBl0 + kt, sBl + lw0);
      async16(gBl1 + kt, sBl + lw1);
    }
    __syncthreads();

    bf16x8 a_h[4], b_h[4], a_l[4], b_l[4];
#pragma unroll
    for (int t = 0; t < 4; ++t) {
      a_h[t] = fAh[quad * 128 + arow + t * 16];
      b_h[t] = fBh[quad * 128 + brow + t * 16];
    }
    if (SPLIT) {
#pragma unroll
      for (int t = 0; t < 4; ++t) {
        a_l[t] = fAl[quad * 128 + arow + t * 16];
        b_l[t] = fBl[quad * 128 + brow + t * 16];
      }
    }
#pragma unroll
    for (int tm = 0; tm < 4; ++tm)
#pragma unroll
      for (int tn = 0; tn < 4; ++tn) {
        acc[tm][tn] = __builtin_amdgcn_mfma_f32_16x16x32_bf16(a_h[tm], b_h[tn], acc[tm][tn], 0, 0, 0);
        if (SPLIT) {
          acc[tm][tn] = __builtin_amdgcn_mfma_f32_16x16x32_bf16(a_h[tm], b_l[tn], acc[tm][tn], 0, 0, 0);
          acc[tm][tn] = __builtin_amdgcn_mfma_f32_16x16x32_bf16(a_l[tm], b_h[tn], acc[tm][tn], 0, 0, 0);
        }
      }
  }

  // epilogue: C/D layout col=lane&15, row=quad*4+i (m89/m91-verified)
  const long crow0 = (long)blockIdx.x * 128 + wm * 64;
  const long ccol0 = (long)blockIdx.y * 128 + wn * 64;
  const long cBase = (long)blockIdx.z * sC;
#pragma unroll
  for (int tn = 0; tn < 4; ++tn) {
    const long gcol = ccol0 + tn * 16 + m16;
    const float bv = OUTSPLIT ? bias[gcol] : 0.0f;
#pragma unroll
    for (int tm = 0; tm < 4; ++tm) {
#pragma unroll
      for (int i = 0; i < 4; ++i) {
        const long grow = crow0 + tm * 16 + quad * 4 + i;
        const long idx = cBase + grow * (long)Nn + gcol;
        const float val = acc[tm][tn][i] + bv;
        if (OUTSPLIT) {
          unsigned short h = f2bf(val);
          Ch[idx] = h;
          Cl[idx] = f2bf(val - bf2f(h));
        } else {
          Cf[idx] = val;
        }
      }
    }
  }
}

// ---------------- P3: per-row (over k) max & 1/sumexp; one wave per row ------
__global__ void k_rowstats(const float* __restrict__ S, float* __restrict__ m1,
                           float* __restrict__ r1) {
  const int lane = threadIdx.x & 63;
  const int wave = threadIdx.x >> 6;
  const long row = (long)blockIdx.x * 4 + wave;
  const f32x4* p = (const f32x4*)(S + (row << 10));
  f32x4 v[4];
#pragma unroll
  for (int j = 0; j < 4; ++j) v[j] = p[lane + j * 64];
  float mx = -3.4e38f;
#pragma unroll
  for (int j = 0; j < 4; ++j)
#pragma unroll
    for (int c = 0; c < 4; ++c) mx = fmaxf(mx, v[j][c]);
#pragma unroll
  for (int off = 32; off > 0; off >>= 1) mx = fmaxf(mx, __shfl_xor(mx, off, 64));
  float s = 0.0f;
#pragma unroll
  for (int j = 0; j < 4; ++j)
#pragma unroll
    for (int c = 0; c < 4; ++c) s += __expf(v[j][c] - mx);
#pragma unroll
  for (int off = 32; off > 0; off >>= 1) s += __shfl_xor(s, off, 64);
  if (lane == 0) { m1[row] = mx; r1[row] = 1.0f / s; }
}

// ---------------- P4: per-column (over l) stats, two-stage -------------------
__global__ void k_colstats_part(const float* __restrict__ S, float* __restrict__ mp,
                                float* __restrict__ sp) {
  const int n = blockIdx.z, lc = blockIdx.y, kc = blockIdx.x;
  const int k = kc * 256 + threadIdx.x;
  const float* p = S + ((long)n << 20) + ((long)(lc * 256) << 10) + k;
  float m = -3.4e38f, s = 0.0f;
  for (int i = 0; i < 256; ++i) {
    const float x = p[(long)i << 10];
    const float nm = fmaxf(m, x);
    s = s * __expf(m - nm) + __expf(x - nm);
    m = nm;
  }
  const long o = ((long)(n * 4 + lc) << 10) + k;
  mp[o] = m; sp[o] = s;
}

__global__ void k_colstats_comb(const float* __restrict__ mp, const float* __restrict__ sp,
                                float* __restrict__ m2, float* __restrict__ r2) {
  const int n = blockIdx.y;
  const int k = blockIdx.x * 256 + threadIdx.x;
  float m = -3.4e38f, s = 0.0f;
#pragma unroll
  for (int c = 0; c < 4; ++c) {
    const long o = ((long)(n * 4 + c) << 10) + k;
    const float mc = mp[o], sc = sp[o];
    const float nm = fmaxf(m, mc);
    s = s * __expf(m - nm) + sc * __expf(mc - nm);
    m = nm;
  }
  m2[((long)n << 10) + k] = m;
  r2[((long)n << 10) + k] = 1.0f / s;
}

// ---------------- P5: A1 = softmax_k(S) bf16 ; A2T = softmax_l(S)^T bf16 -----
__global__ void k_agen(const float* __restrict__ S, const float* __restrict__ m1,
                       const float* __restrict__ r1, const float* __restrict__ m2,
                       const float* __restrict__ r2, unsigned short* __restrict__ A1,
                       unsigned short* __restrict__ A2T) {
  __shared__ float e2[64][65];
  const int n = blockIdx.z;
  const int k0 = blockIdx.x * 64, l0 = blockIdx.y * 64;
  const int q = threadIdx.x >> 4, p = threadIdx.x & 15;
  const long nb = (long)n << 20;
  const int kk = k0 + p * 4;
  const f32x4 mm2 = *(const f32x4*)(m2 + ((long)n << 10) + kk);
  const f32x4 rr2 = *(const f32x4*)(r2 + ((long)n << 10) + kk);
#pragma unroll
  for (int rr = 0; rr < 4; ++rr) {
    const int lrow = rr * 16 + q;
    const int l = l0 + lrow;
    const f32x4 s4 = *(const f32x4*)(S + nb + ((long)l << 10) + kk);
    const float mv = m1[((long)n << 10) + l], rv = r1[((long)n << 10) + l];
    u16x4 o;
#pragma unroll
    for (int j = 0; j < 4; ++j) {
      o[j] = f2bf(__expf(s4[j] - mv) * rv);
      e2[lrow][p * 4 + j] = __expf(s4[j] - mm2[j]) * rr2[j];
    }
    *(u16x4*)(A1 + nb + ((long)l << 10) + kk) = o;
  }
  __syncthreads();
#pragma unroll
  for (int rr = 0; rr < 4; ++rr) {
    const int krow = rr * 16 + q;
    u16x4 o;
#pragma unroll
    for (int j = 0; j < 4; ++j) o[j] = f2bf(e2[p * 4 + j][krow]);
    *(u16x4*)(A2T + nb + ((long)(k0 + krow) << 10) + (l0 + p * 4)) = o;
  }
}

// ---------------- transpose fp32 [n][r][c] -> bf16 [n][c][r] -----------------
__global__ void k_transpose_bf16(const float* __restrict__ in, unsigned short* __restrict__ out) {
  __shared__ float t[64][65];
  const int n = blockIdx.z;
  const int c0 = blockIdx.x * 64, r0 = blockIdx.y * 64;
  const int q = threadIdx.x >> 4, p = threadIdx.x & 15;
  const long nb = (long)n << 20;
#pragma unroll
  for (int rr = 0; rr < 4; ++rr) {
    const int r = rr * 16 + q;
    const f32x4 v = *(const f32x4*)(in + nb + ((long)(r0 + r) << 10) + c0 + p * 4);
#pragma unroll
    for (int j = 0; j < 4; ++j) t[r][p * 4 + j] = v[j];
  }
  __syncthreads();
#pragma unroll
  for (int rr = 0; rr < 4; ++rr) {
    const int c = rr * 16 + q;
    u16x4 o;
#pragma unroll
    for (int j = 0; j < 4; ++j) o[j] = f2bf(t[p * 4 + j][c]);
    *(u16x4*)(out + nb + ((long)(c0 + c) << 10) + (r0 + p * 4)) = o;
  }
}

extern "C" void kernel_launch(void* const* d_in, const int* in_sizes, int n_in,
                              void* d_out, int out_size, void* d_ws, size_t ws_size,
                              hipStream_t stream) {
  const float* a1 = (const float*)d_in[0];
  const float* a2 = (const float*)d_in[1];
  const float* Gw = (const float*)d_in[2];
  const float* Gb = (const float*)d_in[3];
  float* out = (float*)d_out;
  char* ws = (char*)d_ws;
  const size_t MB = 1ull << 20;

  // phase-1 regions
  unsigned short* a1h  = (unsigned short*)(ws + 0 * MB);
  unsigned short* a1l  = (unsigned short*)(ws + 32 * MB);
  unsigned short* a2h  = (unsigned short*)(ws + 64 * MB);
  unsigned short* a2l  = (unsigned short*)(ws + 96 * MB);
  unsigned short* a2ph = (unsigned short*)(ws + 128 * MB);
  unsigned short* a2pl = (unsigned short*)(ws + 160 * MB);
  unsigned short* Gh   = (unsigned short*)(ws + 192 * MB);
  unsigned short* Gl   = (unsigned short*)(ws + 194 * MB);
  char* st = ws + 196 * MB;
  float* m1 = (float*)(st);
  float* r1 = (float*)(st + 64 * 1024);
  float* m2 = (float*)(st + 128 * 1024);
  float* r2 = (float*)(st + 192 * 1024);
  float* mp = (float*)(st + 256 * 1024);
  float* sp = (float*)(st + 512 * 1024);
  // lifetime-reused regions
  float* S            = (float*)(ws + 64 * MB);           // over a2h/a2l (dead after P1)
  unsigned short* A1  = (unsigned short*)(ws + 0 * MB);   // over a1h (dead after P2)
  unsigned short* A2T = (unsigned short*)(ws + 32 * MB);  // over a1l
  unsigned short* a2T = (unsigned short*)(ws + 128 * MB); // over a2ph (dead after P2)
  unsigned short* a1T = (unsigned short*)(ws + 160 * MB); // over a2pl

  const long B1M = 1048576;

  // P0: hi/lo splits
  k_split<<<16384, 256, 0, stream>>>(a1, a1h, a1l, 4194304);
  k_split<<<16384, 256, 0, stream>>>(a2, a2h, a2l, 4194304);
  k_split<<<1024, 256, 0, stream>>>(Gw, Gh, Gl, 262144);

  // P1: a2p[m][e] = a2[m][:] . Gw[e][:] + Gb[e]   (M=16384, split in, split out)
  k_gemm_bt<true, true><<<dim3(128, 8, 1), 256, 0, stream>>>(
      a2h, a2l, Gh, Gl, Gb, nullptr, a2ph, a2pl, 1024, 1024, 0, 0, 0);

  // P2: S[n][l][k] = a1[n][l][:] . a2p[n][k][:]   (fp32 out)
  k_gemm_bt<true, false><<<dim3(8, 8, 16), 256, 0, stream>>>(
      a1h, a1l, a2ph, a2pl, nullptr, S, nullptr, nullptr, 1024, 1024, B1M, B1M, B1M);

  // P3/P4: softmax stats
  k_rowstats<<<4096, 256, 0, stream>>>(S, m1, r1);
  k_colstats_part<<<dim3(4, 4, 16), 256, 0, stream>>>(S, mp, sp);
  k_colstats_comb<<<dim3(4, 16), 256, 0, stream>>>(mp, sp, m2, r2);

  // P5: A1 (softmax over k) and A2T (softmax over l, transposed) in bf16
  k_agen<<<dim3(16, 16, 16), 256, 0, stream>>>(S, m1, r1, m2, r2, A1, A2T);

  // bf16 transposes of the raw inputs (for B^T-form GEMMs)
  k_transpose_bf16<<<dim3(16, 16, 16), 256, 0, stream>>>(a2, a2T);
  k_transpose_bf16<<<dim3(16, 16, 16), 256, 0, stream>>>(a1, a1T);

  // P6: M1[n][l][d] = A1[n][l][:] . a2T[n][d][:]
  k_gemm_bt<false, false><<<dim3(8, 8, 16), 256, 0, stream>>>(
      A1, nullptr, a2T, nullptr, nullptr, out, nullptr, nullptr, 1024, 1024, B1M, B1M, B1M);

  // P7: M2[n][k][d] = A2T[n][k][:] . a1T[n][d][:]
  k_gemm_bt<false, false><<<dim3(8, 8, 16), 256, 0, stream>>>(
      A2T, nullptr, a1T, nullptr, nullptr, out + 16777216, nullptr, nullptr,
      1024, 1024, B1M, B1M, B1M);
}

// Round 2
// 797.254 us; speedup vs baseline: 1.0320x; 1.0320x over previous
//
#include <hip/hip_runtime.h>
#include <stdint.h>

#define DEVI __device__ __forceinline__

typedef __attribute__((ext_vector_type(4))) float f32x4;
typedef __attribute__((ext_vector_type(8))) short bf16x8;
typedef __attribute__((ext_vector_type(4))) unsigned short u16x4;

DEVI unsigned short f2bf(float x) {
  union { float f; uint32_t u; } v; v.f = x;
  uint32_t r = v.u + 0x7FFFu + ((v.u >> 16) & 1u);  // RNE
  return (unsigned short)(r >> 16);
}
DEVI float bf2f(unsigned short h) {
  union { uint32_t u; float f; } v; v.u = ((uint32_t)h) << 16;
  return v.f;
}

DEVI void async16(const void* g, void* l) {
  __builtin_amdgcn_global_load_lds((__attribute__((address_space(1))) void*)g,
                                   (__attribute__((address_space(3))) void*)l,
                                   16, 0, 0);
}

// ---------------- P0: fp32 -> bf16 hi/lo split (a1 & a2 in one launch) -------
__global__ void k_split2(const float* __restrict__ x0, unsigned short* __restrict__ h0,
                         unsigned short* __restrict__ l0,
                         const float* __restrict__ x1, unsigned short* __restrict__ h1,
                         unsigned short* __restrict__ l1) {
  const long i = (long)blockIdx.x * 256 + threadIdx.x;
  const float* x = blockIdx.y ? x1 : x0;
  unsigned short* hh = blockIdx.y ? h1 : h0;
  unsigned short* ll = blockIdx.y ? l1 : l0;
  const f32x4 v = ((const f32x4*)x)[i];
  u16x4 H, L;
#pragma unroll
  for (int j = 0; j < 4; ++j) {
    H[j] = f2bf(v[j]);
    L[j] = f2bf(v[j] - bf2f(H[j]));
  }
  ((u16x4*)hh)[i] = H;
  ((u16x4*)ll)[i] = L;
}

__global__ void k_split(const float* __restrict__ x, unsigned short* __restrict__ hi,
                        unsigned short* __restrict__ lo, const long n4) {
  const long i = (long)blockIdx.x * 256 + threadIdx.x;
  if (i >= n4) return;
  const f32x4 v = ((const f32x4*)x)[i];
  u16x4 H, L;
#pragma unroll
  for (int j = 0; j < 4; ++j) {
    H[j] = f2bf(v[j]);
    L[j] = f2bf(v[j] - bf2f(H[j]));
  }
  ((u16x4*)hi)[i] = H;
  ((u16x4*)lo)[i] = L;
}

// ---------------- GEMM: C = A * B^T  (A: [M][Kd], B: [Nn][Kd], C: [M][Nn]) ----
// 128x128 tile, BK=32, 4 waves (2x2), 4x4 MFMA 16x16x32 tiles per wave.
// XCD-aware swizzle: blocks 8 apart (same XCD) share (x,z) and sweep y, so the
// 512 KB A-tile stays L2-resident across its 8 consumers. Requires gy==8,
// gx = 1<<lgx. DUAL: z>=16 switches to second (A,B,C) set (P6/P7 merged).
template<bool SPLIT, bool OUTSPLIT, bool DUAL>
__global__ __launch_bounds__(256, 2)
void k_gemm_bt(const unsigned short* __restrict__ Ah, const unsigned short* __restrict__ Al,
               const unsigned short* __restrict__ Bh, const unsigned short* __restrict__ Bl,
               const float* __restrict__ bias,
               float* __restrict__ Cf, unsigned short* __restrict__ Ch,
               unsigned short* __restrict__ Cl,
               const unsigned short* __restrict__ Ax, const unsigned short* __restrict__ Bx,
               float* __restrict__ Cx,
               const int Kd, const int Nn,
               const long sA, const long sB, const long sC, const int lgx) {
  __shared__ __align__(16) unsigned short smem[SPLIT ? 16384 : 8192];
  const int tid  = threadIdx.x;
  const int lane = tid & 63;
  const int wave = tid >> 6;
  const int wm = wave >> 1, wn = wave & 1;
  const int m16 = lane & 15, quad = lane >> 4;

  // swizzle decode (bijective: lin = c + 8*y + 64*h ; u = c + 8*h)
  const int lin = blockIdx.x + gridDim.x * (blockIdx.y + gridDim.y * blockIdx.z);
  const int by = (lin >> 3) & 7;
  const int u  = (lin & 7) | ((lin >> 6) << 3);
  const int bx = u & ((1 << lgx) - 1);
  int bz = u >> lgx;

  const unsigned short* Ahp = Ah;
  const unsigned short* Bhp = Bh;
  float* Cp = Cf;
  if (DUAL && bz >= 16) { Ahp = Ax; Bhp = Bx; Cp = Cx; bz -= 16; }

  const long aTile = (long)bz * sA + (long)bx * 128 * Kd;
  const long bTile = (long)bz * sB + (long)by * 128 * Kd;

  // staging chunks: t in {0,1}: c = t*256 + tid ; row = c&127 ; kg = c>>7
  const int rs  = tid & 127;
  const int kg0 = tid >> 7;
  const int kg1 = 2 + (tid >> 7);
  const long aoff0 = (long)rs * Kd + kg0 * 8;
  const long aoff1 = (long)rs * Kd + kg1 * 8;

  const unsigned short* gAh0 = Ahp + aTile + aoff0;
  const unsigned short* gAh1 = Ahp + aTile + aoff1;
  const unsigned short* gBh0 = Bhp + bTile + aoff0;
  const unsigned short* gBh1 = Bhp + bTile + aoff1;
  const unsigned short* gAl0 = SPLIT ? (Al + aTile + aoff0) : (const unsigned short*)0;
  const unsigned short* gAl1 = SPLIT ? (Al + aTile + aoff1) : (const unsigned short*)0;
  const unsigned short* gBl0 = SPLIT ? (Bl + bTile + aoff0) : (const unsigned short*)0;
  const unsigned short* gBl1 = SPLIT ? (Bl + bTile + aoff1) : (const unsigned short*)0;

  unsigned short* sAh = smem;
  unsigned short* sBh = smem + 4096;
  unsigned short* sAl = smem + (SPLIT ? 8192 : 0);
  unsigned short* sBl = smem + (SPLIT ? 12288 : 0);
  const int lw0 = (wave * 64) * 8;         // ushort offset, t=0
  const int lw1 = (256 + wave * 64) * 8;   // t=1

  f32x4 acc[4][4];
#pragma unroll
  for (int i = 0; i < 4; ++i)
#pragma unroll
    for (int j = 0; j < 4; ++j) acc[i][j] = (f32x4){0.0f, 0.0f, 0.0f, 0.0f};

  const int arow = wm * 64 + m16;
  const int brow = wn * 64 + m16;
  const bf16x8* fAh = (const bf16x8*)sAh;
  const bf16x8* fBh = (const bf16x8*)sBh;
  const bf16x8* fAl = (const bf16x8*)sAl;
  const bf16x8* fBl = (const bf16x8*)sBl;

  for (int kt = 0; kt < Kd; kt += 32) {
    __syncthreads();
    async16(gAh0 + kt, sAh + lw0);
    async16(gAh1 + kt, sAh + lw1);
    async16(gBh0 + kt, sBh + lw0);
    async16(gBh1 + kt, sBh + lw1);
    if (SPLIT) {
      async16(gAl0 + kt, sAl + lw0);
      async16(gAl1 + kt, sAl + lw1);
      async16(gBl0 + kt, sBl + lw0);
      async16(gBl1 + kt, sBl + lw1);
    }
    __syncthreads();

    bf16x8 a_h[4], b_h[4], a_l[4], b_l[4];
#pragma unroll
    for (int t = 0; t < 4; ++t) {
      a_h[t] = fAh[quad * 128 + arow + t * 16];
      b_h[t] = fBh[quad * 128 + brow + t * 16];
    }
    if (SPLIT) {
#pragma unroll
      for (int t = 0; t < 4; ++t) {
        a_l[t] = fAl[quad * 128 + arow + t * 16];
        b_l[t] = fBl[quad * 128 + brow + t * 16];
      }
    }
#pragma unroll
    for (int tm = 0; tm < 4; ++tm)
#pragma unroll
      for (int tn = 0; tn < 4; ++tn) {
        acc[tm][tn] = __builtin_amdgcn_mfma_f32_16x16x32_bf16(a_h[tm], b_h[tn], acc[tm][tn], 0, 0, 0);
        if (SPLIT) {
          acc[tm][tn] = __builtin_amdgcn_mfma_f32_16x16x32_bf16(a_h[tm], b_l[tn], acc[tm][tn], 0, 0, 0);
          acc[tm][tn] = __builtin_amdgcn_mfma_f32_16x16x32_bf16(a_l[tm], b_h[tn], acc[tm][tn], 0, 0, 0);
        }
      }
  }

  // epilogue: C/D layout col=lane&15, row=quad*4+i (m89/m91-verified)
  const long crow0 = (long)bx * 128 + wm * 64;
  const long ccol0 = (long)by * 128 + wn * 64;
  const long cBase = (long)bz * sC;
#pragma unroll
  for (int tn = 0; tn < 4; ++tn) {
    const long gcol = ccol0 + tn * 16 + m16;
    const float bv = OUTSPLIT ? bias[gcol] : 0.0f;
#pragma unroll
    for (int tm = 0; tm < 4; ++tm) {
#pragma unroll
      for (int i = 0; i < 4; ++i) {
        const long grow = crow0 + tm * 16 + quad * 4 + i;
        const long idx = cBase + grow * (long)Nn + gcol;
        const float val = acc[tm][tn][i] + bv;
        if (OUTSPLIT) {
          unsigned short h = f2bf(val);
          Ch[idx] = h;
          Cl[idx] = f2bf(val - bf2f(h));
        } else {
          Cp[idx] = val;
        }
      }
    }
  }
}

// ---------------- P3+P4a fused: row stats & column partial stats -------------
__global__ void k_rcstats(const float* __restrict__ S, float* __restrict__ m1,
                          float* __restrict__ r1, float* __restrict__ mp,
                          float* __restrict__ sp) {
  if (blockIdx.x < 4096) {
    // per-row (over k) max & 1/sumexp; one wave per row
    const int lane = threadIdx.x & 63;
    const int wave = threadIdx.x >> 6;
    const long row = (long)blockIdx.x * 4 + wave;
    const f32x4* p = (const f32x4*)(S + (row << 10));
    f32x4 v[4];
#pragma unroll
    for (int j = 0; j < 4; ++j) v[j] = p[lane + j * 64];
    float mx = -3.4e38f;
#pragma unroll
    for (int j = 0; j < 4; ++j)
#pragma unroll
      for (int c = 0; c < 4; ++c) mx = fmaxf(mx, v[j][c]);
#pragma unroll
    for (int off = 32; off > 0; off >>= 1) mx = fmaxf(mx, __shfl_xor(mx, off, 64));
    float s = 0.0f;
#pragma unroll
    for (int j = 0; j < 4; ++j)
#pragma unroll
      for (int c = 0; c < 4; ++c) s += __expf(v[j][c] - mx);
#pragma unroll
    for (int off = 32; off > 0; off >>= 1) s += __shfl_xor(s, off, 64);
    if (lane == 0) { m1[row] = mx; r1[row] = 1.0f / s; }
  } else {
    // per-column (over l) partial stats, 256-row strips
    const int b = blockIdx.x - 4096;
    const int kc = b & 3, lc = (b >> 2) & 3, n = b >> 4;
    const int k = kc * 256 + threadIdx.x;
    const float* p = S + ((long)n << 20) + ((long)(lc * 256) << 10) + k;
    float m = -3.4e38f, s = 0.0f;
    for (int i = 0; i < 256; ++i) {
      const float x = p[(long)i << 10];
      const float nm = fmaxf(m, x);
      s = s * __expf(m - nm) + __expf(x - nm);
      m = nm;
    }
    const long o = ((long)(n * 4 + lc) << 10) + k;
    mp[o] = m; sp[o] = s;
  }
}

__global__ void k_colstats_comb(const float* __restrict__ mp, const float* __restrict__ sp,
                                float* __restrict__ m2, float* __restrict__ r2) {
  const int n = blockIdx.y;
  const int k = blockIdx.x * 256 + threadIdx.x;
  float m = -3.4e38f, s = 0.0f;
#pragma unroll
  for (int c = 0; c < 4; ++c) {
    const long o = ((long)(n * 4 + c) << 10) + k;
    const float mc = mp[o], sc = sp[o];
    const float nm = fmaxf(m, mc);
    s = s * __expf(m - nm) + sc * __expf(mc - nm);
    m = nm;
  }
  m2[((long)n << 10) + k] = m;
  r2[((long)n << 10) + k] = 1.0f / s;
}

// ---------------- P5: A1 = softmax_k(S) bf16 ; A2T = softmax_l(S)^T bf16 -----
__global__ void k_agen(const float* __restrict__ S, const float* __restrict__ m1,
                       const float* __restrict__ r1, const float* __restrict__ m2,
                       const float* __restrict__ r2, unsigned short* __restrict__ A1,
                       unsigned short* __restrict__ A2T) {
  __shared__ float e2[64][65];
  const int n = blockIdx.z;
  const int k0 = blockIdx.x * 64, l0 = blockIdx.y * 64;
  const int q = threadIdx.x >> 4, p = threadIdx.x & 15;
  const long nb = (long)n << 20;
  const int kk = k0 + p * 4;
  const f32x4 mm2 = *(const f32x4*)(m2 + ((long)n << 10) + kk);
  const f32x4 rr2 = *(const f32x4*)(r2 + ((long)n << 10) + kk);
#pragma unroll
  for (int rr = 0; rr < 4; ++rr) {
    const int lrow = rr * 16 + q;
    const int l = l0 + lrow;
    const f32x4 s4 = *(const f32x4*)(S + nb + ((long)l << 10) + kk);
    const float mv = m1[((long)n << 10) + l], rv = r1[((long)n << 10) + l];
    u16x4 o;
#pragma unroll
    for (int j = 0; j < 4; ++j) {
      o[j] = f2bf(__expf(s4[j] - mv) * rv);
      e2[lrow][p * 4 + j] = __expf(s4[j] - mm2[j]) * rr2[j];
    }
    *(u16x4*)(A1 + nb + ((long)l << 10) + kk) = o;
  }
  __syncthreads();
#pragma unroll
  for (int rr = 0; rr < 4; ++rr) {
    const int krow = rr * 16 + q;
    u16x4 o;
#pragma unroll
    for (int j = 0; j < 4; ++j) o[j] = f2bf(e2[p * 4 + j][krow]);
    *(u16x4*)(A2T + nb + ((long)(k0 + krow) << 10) + (l0 + p * 4)) = o;
  }
}

// ---------------- transpose fp32 [n][r][c] -> bf16 [n][c][r], both inputs ----
__global__ void k_transpose2(const float* __restrict__ in0, unsigned short* __restrict__ out0,
                             const float* __restrict__ in1, unsigned short* __restrict__ out1) {
  __shared__ float t[64][65];
  const int zz = blockIdx.z;
  const int n = zz & 15;
  const float* in = (zz < 16) ? in0 : in1;
  unsigned short* out = (zz < 16) ? out0 : out1;
  const int c0 = blockIdx.x * 64, r0 = blockIdx.y * 64;
  const int q = threadIdx.x >> 4, p = threadIdx.x & 15;
  const long nb = (long)n << 20;
#pragma unroll
  for (int rr = 0; rr < 4; ++rr) {
    const int r = rr * 16 + q;
    const f32x4 v = *(const f32x4*)(in + nb + ((long)(r0 + r) << 10) + c0 + p * 4);
#pragma unroll
    for (int j = 0; j < 4; ++j) t[r][p * 4 + j] = v[j];
  }
  __syncthreads();
#pragma unroll
  for (int rr = 0; rr < 4; ++rr) {
    const int c = rr * 16 + q;
    u16x4 o;
#pragma unroll
    for (int j = 0; j < 4; ++j) o[j] = f2bf(t[p * 4 + j][c]);
    *(u16x4*)(out + nb + ((long)(c0 + c) << 10) + (r0 + p * 4)) = o;
  }
}

extern "C" void kernel_launch(void* const* d_in, const int* in_sizes, int n_in,
                              void* d_out, int out_size, void* d_ws, size_t ws_size,
                              hipStream_t stream) {
  const float* a1 = (const float*)d_in[0];
  const float* a2 = (const float*)d_in[1];
  const float* Gw = (const float*)d_in[2];
  const float* Gb = (const float*)d_in[3];
  float* out = (float*)d_out;
  char* ws = (char*)d_ws;
  const size_t MB = 1ull << 20;

  // phase-1 regions
  unsigned short* a1h  = (unsigned short*)(ws + 0 * MB);
  unsigned short* a1l  = (unsigned short*)(ws + 32 * MB);
  unsigned short* a2h  = (unsigned short*)(ws + 64 * MB);
  unsigned short* a2l  = (unsigned short*)(ws + 96 * MB);
  unsigned short* a2ph = (unsigned short*)(ws + 128 * MB);
  unsigned short* a2pl = (unsigned short*)(ws + 160 * MB);
  unsigned short* Gh   = (unsigned short*)(ws + 192 * MB);
  unsigned short* Gl   = (unsigned short*)(ws + 194 * MB);
  char* st = ws + 196 * MB;
  float* m1 = (float*)(st);
  float* r1 = (float*)(st + 64 * 1024);
  float* m2 = (float*)(st + 128 * 1024);
  float* r2 = (float*)(st + 192 * 1024);
  float* mp = (float*)(st + 256 * 1024);
  float* sp = (float*)(st + 512 * 1024);
  // lifetime-reused regions
  float* S            = (float*)(ws + 64 * MB);           // over a2h/a2l (dead after P1)
  unsigned short* A1  = (unsigned short*)(ws + 0 * MB);   // over a1h (dead after P2)
  unsigned short* A2T = (unsigned short*)(ws + 32 * MB);  // over a1l
  unsigned short* a2T = (unsigned short*)(ws + 128 * MB); // over a2ph (dead after P2)
  unsigned short* a1T = (unsigned short*)(ws + 160 * MB); // over a2pl

  const long B1M = 1048576;

  // P0: hi/lo splits (a1 & a2 fused; G separate)
  k_split2<<<dim3(16384, 2), 256, 0, stream>>>(a1, a1h, a1l, a2, a2h, a2l);
  k_split<<<1024, 256, 0, stream>>>(Gw, Gh, Gl, 262144);

  // P1: a2p[m][e] = a2[m][:] . Gw[e][:] + Gb[e]   (M=16384, split in/out)
  k_gemm_bt<true, true, false><<<dim3(128, 8, 1), 256, 0, stream>>>(
      a2h, a2l, Gh, Gl, Gb, nullptr, a2ph, a2pl, nullptr, nullptr, nullptr,
      1024, 1024, 0, 0, 0, 7);

  // P2: S[n][l][k] = a1[n][l][:] . a2p[n][k][:]   (fp32 out)
  k_gemm_bt<true, false, false><<<dim3(8, 8, 16), 256, 0, stream>>>(
      a1h, a1l, a2ph, a2pl, nullptr, S, nullptr, nullptr, nullptr, nullptr, nullptr,
      1024, 1024, B1M, B1M, B1M, 3);

  // P3+P4a fused: row stats + col partial stats (one S read each)
  k_rcstats<<<4352, 256, 0, stream>>>(S, m1, r1, mp, sp);
  k_colstats_comb<<<dim3(4, 16), 256, 0, stream>>>(mp, sp, m2, r2);

  // P5: A1 (softmax over k) and A2T (softmax over l, transposed) in bf16
  k_agen<<<dim3(16, 16, 16), 256, 0, stream>>>(S, m1, r1, m2, r2, A1, A2T);

  // bf16 transposes of the raw inputs (both in one launch)
  k_transpose2<<<dim3(16, 16, 32), 256, 0, stream>>>(a2, a2T, a1, a1T);

  // P6+P7 merged: z<16 -> M1 = A1 . a2T^T ; z>=16 -> M2 = A2T . a1T^T
  k_gemm_bt<false, false, true><<<dim3(8, 8, 32), 256, 0, stream>>>(
      A1, nullptr, a2T, nullptr, nullptr, out, nullptr, nullptr,
      A2T, a1T, out + 16777216,
      1024, 1024, B1M, B1M, B1M, 3);
}